// Round 18
// baseline (172.030 us; speedup 1.0000x reference)
//
#include <hip/hip_runtime.h>
#include <hip/hip_cooperative_groups.h>

#define KDIM 256
#define DWIN 20
#define NOBS 8192
#define TAU  20
#define TROWS (NOBS - TAU)          // 8172
#define KTOT  (DWIN * KDIM)         // 5120
#define KS128 (KTOT / 128)          // 40 K-steps of 128
#define QS128 (KS128 / 4)           // 10 per wave (K-quarter)

#define BM 64
#define NBLK_M ((TROWS + BM - 1) / BM)   // 128
#define NBLK   (NBLK_M * 4)              // 512

#define AROWS 83                     // 64 + DWIN - 1
#define APITCH 272                   // 256B data + 16B pad (R10/R13-proven)

#define SH_BYTES 32768               // static shared: A panel 22.6KB / exchange 32KB

typedef float f32x4 __attribute__((ext_vector_type(4)));
typedef int   i32x4 __attribute__((ext_vector_type(4)));
typedef int   i32x8 __attribute__((ext_vector_type(8)));

// ws layout (bytes): Bf8 (1,310,720) | A8 (2,097,152)
#define WS_BF    0u
#define WS_A8    2097152u
#define WS_NEED  (WS_A8 + 2097152u + 8192u)

__device__ __forceinline__ unsigned int pk4_fp8(float a, float b, float c, float d) {
    int lo = __builtin_amdgcn_cvt_pk_fp8_f32(a, b, 0, false);
    return (unsigned int)__builtin_amdgcn_cvt_pk_fp8_f32(c, d, lo, true);
}

// ---------- device fn: B-fragment prep for column n (R15-verified) ----------
// Bf8[((ks*16+nt)*64 + g*16 + qn)*32 + half*16 + j'] = e4m3(B[k][n]),
//   k = ks*128 + g*32 + half*16 + j', n = nt*16 + qn, B[k][n] = beta1[n][k&255][k>>8]
__device__ __forceinline__ void prep_b_block(int n, int tid,
                                             const float* __restrict__ beta1,
                                             unsigned char* __restrict__ Bf8,
                                             float* L, float* out)
{
    if (n == 0 && tid == 0) out[0] = 0.f;
    const float* __restrict__ src = beta1 + (size_t)n * KTOT;
    for (int f = tid; f < KTOT; f += 256) {
        int b = f / DWIN, a = f - b * DWIN;
        L[a * 260 + b] = src[f];           // transposed, bank-stride 4
    }
    __syncthreads();
    const int nt = n >> 4, qn = n & 15;
    for (int c = tid; c < KS128 * 8; c += 256) {      // c = ks*8 + g*2 + half
        const int ks = c >> 3, g = (c >> 1) & 3, half = c & 1;
        const int kb = ks * 128 + g * 32 + half * 16;
        const float* Lp = &L[(kb >> 8) * 260 + (kb & 255)];
        i32x4 w;
#pragma unroll
        for (int u = 0; u < 4; ++u) {
            float4 v = *(const float4*)(Lp + u * 4);
            w[u] = (int)pk4_fp8(v.x, v.y, v.z, v.w);
        }
        *(i32x4*)&Bf8[(((size_t)ks * 16 + nt) * 64 + g * 16 + qn) * 32 + half * 16] = w;
    }
}

__device__ __forceinline__ void prep_a_block(int blk, int tid,
                                             const float* __restrict__ obs,
                                             unsigned int* __restrict__ A8)
{
    const int base = blk * 8192;
#pragma unroll 4
    for (int u = tid; u < 8192; u += 256) {
        float4 v = ((const float4*)obs)[base + u];
        A8[base + u] = pk4_fp8(v.x, v.y, v.z, v.w);
    }
}

// ---------- device fn: gemm block (R15-proven loop + 32KB 2-round exchange) ----------
__device__ __forceinline__ void gemm_block(int bid, int tid,
                                           const float* __restrict__ obs,
                                           const float* __restrict__ beta0,
                                           const unsigned char* __restrict__ Bf8,
                                           const unsigned char* __restrict__ A8,
                                           float* __restrict__ out,
                                           char* shbuf)
{
    const int lane = tid & 63;
    const int kq   = tid >> 6;     // wave id: owns K128-steps [10kq, 10kq+10)
    const int g = lane >> 4;
    const int q = lane & 15;
    const int nb = bid & 3;
    const int mb = bid >> 2;
    const int i0 = mb * BM;

    char* ldsA8 = shbuf;           // AROWS x APITCH fp8 (22,576 B)
    const char* bbase = (const char*)Bf8 + (size_t)(nb * 4) * 2048 + (size_t)lane * 32;

#define LOADB8(dst, s)                                                           \
    {                                                                            \
        const char* _p = bbase + (size_t)(10 * kq + ((s) < QS128 ? (s) : QS128 - 1)) * 32768; \
        _Pragma("unroll")                                                        \
        for (int t = 0; t < 4; ++t)                                              \
            dst[t] = *(const i32x8*)(_p + t * 2048);                             \
    }

    i32x8 rbA[4], rbB[4];
    LOADB8(rbA, 0)

    // stage A panel from pre-packed A8 (row stride = 256 BYTES — R15-proven)
    for (int idx = tid; idx < AROWS * 16; idx += 256) {
        const int row = idx >> 4, c16 = idx & 15;
        const int grow = min(i0 + row, NOBS - 1);
        i32x4 v = *(const i32x4*)(A8 + (size_t)grow * 256 + c16 * 16);
        *(i32x4*)(ldsA8 + row * APITCH + c16 * 16) = v;
    }
    __syncthreads();

    f32x4 acc[4][4];
#pragma unroll
    for (int m = 0; m < 4; ++m)
#pragma unroll
        for (int t = 0; t < 4; ++t)
            acc[m][t] = (f32x4){0.f, 0.f, 0.f, 0.f};

#define COMPUTE8(s, breg)                                                        \
    {                                                                            \
        const int _ks = 10 * kq + (s);                                           \
        const int _aro  = _ks >> 1;                                              \
        const int _acol = (_ks & 1) * 128 + g * 32;                              \
        i32x8 _af[4];                                                            \
        _Pragma("unroll")                                                        \
        for (int m = 0; m < 4; ++m)                                              \
            _af[m] = *(const i32x8*)(ldsA8 + (m * 16 + q + _aro) * APITCH + _acol); \
        __builtin_amdgcn_s_setprio(1);                                           \
        _Pragma("unroll")                                                        \
        for (int t = 0; t < 4; ++t)                                              \
            _Pragma("unroll")                                                    \
            for (int m = 0; m < 4; ++m)                                          \
                acc[m][t] = __builtin_amdgcn_mfma_scale_f32_16x16x128_f8f6f4(    \
                    _af[m], (breg)[t], acc[m][t], 0, 0, 0, 0x7f, 0, 0x7f);       \
        __builtin_amdgcn_s_setprio(0);                                           \
    }

#pragma unroll 1
    for (int s = 0; s < QS128; s += 2) {
        LOADB8(rbB, s + 1)
        COMPUTE8(s, rbA)
        if (s + 2 < QS128) LOADB8(rbA, s + 2)
        COMPUTE8(s + 1, rbB)
    }

    // --- 2-round m-half exchange (32KB peak), wave kq reads band kq ---
    f32x4* pc = (f32x4*)shbuf;
    f32x4 bsum[4] = {};
#pragma unroll
    for (int r2 = 0; r2 < 2; ++r2) {
        __syncthreads();                        // pc region free
#pragma unroll
        for (int m2 = 0; m2 < 2; ++m2)
#pragma unroll
            for (int t = 0; t < 4; ++t)
                pc[((kq * 8 + m2 * 4 + t) << 6) + lane] = acc[2 * r2 + m2][t];
        __syncthreads();
        if ((kq >> 1) == r2) {
            const int m2 = kq & 1;
#pragma unroll
            for (int t = 0; t < 4; ++t) {
                f32x4 ssum = pc[((m2 * 4 + t) << 6) + lane];
#pragma unroll
                for (int wp = 1; wp < 4; ++wp)
                    ssum += pc[((wp * 8 + m2 * 4 + t) << 6) + lane];
                bsum[t] = ssum;
            }
        }
    }
    __syncthreads();                            // all pc reads complete

    // --- fused epilogue: wave kq writes band m=kq (rows i0+kq*16 .. +15) ---
    double part = 0.0;
#pragma unroll
    for (int t = 0; t < 4; ++t) {
        const int col = nb * 64 + t * 16 + q;
        const float b0v = beta0[col];
#pragma unroll
        for (int r = 0; r < 4; ++r) {
            const int row = i0 + kq * 16 + 4 * g + r;   // C/D: row=(lane>>4)*4+reg
            if (row < TROWS) {
                float lam = bsum[t][r] + b0v;
                out[1 + (size_t)row * KDIM + col] = lam;
                float o = obs[(size_t)(row + TAU) * KDIM + col];
                part += (double)o * (double)__logf(lam) - (double)lam;
            }
        }
    }

#pragma unroll
    for (int off = 32; off > 0; off >>= 1) part += __shfl_down(part, off, 64);
    double* sred = (double*)shbuf;              // overlaps pc (post-barrier safe)
    if (lane == 0) sred[kq] = part;
    __syncthreads();
    if (tid == 0)
        atomicAdd(out, (float)(sred[0] + sred[1] + sred[2] + sred[3]));
}

// ---------- fused cooperative kernel: prep -> fence+grid.sync -> gemm ----------
__global__ __launch_bounds__(256, 2)
void fused_kernel(const float* __restrict__ obs,
                  const float* __restrict__ beta0,
                  const float* __restrict__ beta1,
                  unsigned char* __restrict__ Bf8,
                  unsigned int* __restrict__ A8,
                  float* __restrict__ out)
{
    __shared__ char shbuf[SH_BYTES];
    const int tid = threadIdx.x;
    const int bid = blockIdx.x;

    if (bid < KDIM) {
        prep_b_block(bid, tid, beta1, Bf8, (float*)shbuf, out);
    } else if (bid < KDIM + 64) {
        prep_a_block(bid - KDIM, tid, obs, A8);
    }

    __threadfence();                      // device-scope visibility across XCDs
    cooperative_groups::this_grid().sync();

    gemm_block(bid, tid, obs, beta0, Bf8, (const unsigned char*)A8, out, shbuf);
}

// ---------- standalone two-dispatch fallback (R15-equivalent) ----------
__global__ __launch_bounds__(256)
void prep_kernel(const float* __restrict__ beta1,
                 const float* __restrict__ obs,
                 unsigned char* __restrict__ Bf8,
                 unsigned int* __restrict__ A8,
                 float* __restrict__ out)
{
    __shared__ float L[DWIN * 260];   // 20,800 B
    if (blockIdx.x < KDIM) prep_b_block(blockIdx.x, threadIdx.x, beta1, Bf8, L, out);
    else                   prep_a_block(blockIdx.x - KDIM, threadIdx.x, obs, A8);
}

__global__ __launch_bounds__(256, 2)
void gemm_kernel(const float* __restrict__ obs,
                 const float* __restrict__ beta0,
                 const unsigned char* __restrict__ Bf8,
                 const unsigned char* __restrict__ A8,
                 float* __restrict__ out)
{
    __shared__ char shbuf[SH_BYTES];
    gemm_block(blockIdx.x, threadIdx.x, obs, beta0, Bf8, A8, out, shbuf);
}

// ================= fallback fp32 path (R1, proven) =================
#define BM_OLD 16
#define NBLK_OLD ((TROWS + BM_OLD - 1) / BM_OLD)   // 511

__global__ __launch_bounds__(KDIM, 2)
void old_lam_kernel(const float* __restrict__ obs,
                    const float* __restrict__ beta0,
                    const float* __restrict__ beta1,
                    float* __restrict__ out,
                    double* __restrict__ partials)
{
    const int k  = threadIdx.x;
    const int i0 = blockIdx.x * BM_OLD;
    const int nr = min(BM_OLD, TROWS - i0);
    const int smax = nr + DWIN - 1;

    float acc[BM_OLD];
#pragma unroll
    for (int r = 0; r < BM_OLD; ++r) acc[r] = 0.f;

    const float* __restrict__ b1k = beta1 + (size_t)k * (KDIM * DWIN);

    for (int b = 0; b < KDIM; ++b) {
        float br[DWIN];
        const float4* qd = (const float4*)(b1k + b * DWIN);
#pragma unroll
        for (int v = 0; v < DWIN / 4; ++v) {
            float4 t = qd[v];
            br[4*v+0] = t.x; br[4*v+1] = t.y; br[4*v+2] = t.z; br[4*v+3] = t.w;
        }
        float wv[BM_OLD + DWIN - 1];
#pragma unroll
        for (int s = 0; s < BM_OLD + DWIN - 1; ++s)
            wv[s] = (s < smax) ? obs[(size_t)(i0 + s) * KDIM + b] : 0.f;
#pragma unroll
        for (int r = 0; r < BM_OLD; ++r)
#pragma unroll
            for (int a = 0; a < DWIN; ++a)
                acc[r] = fmaf(wv[r + a], br[a], acc[r]);
    }

    const float b0 = beta0[k];
    double part = 0.0;
    for (int r = 0; r < nr; ++r) {
        float lam = acc[r] + b0;
        out[1 + (size_t)(i0 + r) * KDIM + k] = lam;
        float o = obs[(size_t)(i0 + r + TAU) * KDIM + k];
        part += (double)(o * logf(lam) - lam);
    }

    __shared__ double sred2[KDIM];
    sred2[k] = part;
    __syncthreads();
    for (int off = KDIM / 2; off > 0; off >>= 1) {
        if (k < off) sred2[k] += sred2[k + off];
        __syncthreads();
    }
    if (k == 0) partials[blockIdx.x] = sred2[0];
}

__global__ void reduce_final_kernel(const double* __restrict__ partials,
                                    float* __restrict__ out, int n)
{
    __shared__ double sr[256];
    double v = 0.0;
    for (int i = threadIdx.x; i < n; i += 256) v += partials[i];
    sr[threadIdx.x] = v;
    __syncthreads();
    for (int off = 128; off > 0; off >>= 1) {
        if (threadIdx.x < off) sr[threadIdx.x] += sr[threadIdx.x + off];
        __syncthreads();
    }
    if (threadIdx.x == 0) out[0] = (float)sr[0];
}
// ===================================================================

extern "C" void kernel_launch(void* const* d_in, const int* in_sizes, int n_in,
                              void* d_out, int out_size, void* d_ws, size_t ws_size,
                              hipStream_t stream)
{
    const float* obs   = (const float*)d_in[0];
    const float* beta0 = (const float*)d_in[1];
    const float* beta1 = (const float*)d_in[2];
    float* out = (float*)d_out;

    if (ws_size >= (size_t)WS_NEED) {
        unsigned char* Bf8 = (unsigned char*)d_ws + WS_BF;
        unsigned int*  A8  = (unsigned int*)((char*)d_ws + WS_A8);

        void* args[] = { (void*)&obs, (void*)&beta0, (void*)&beta1,
                         (void*)&Bf8, (void*)&A8, (void*)&out };
        hipError_t err = hipLaunchCooperativeKernel(
            reinterpret_cast<const void*>(fused_kernel),
            dim3(NBLK), dim3(256), args, 0, stream);

        if (err != hipSuccess) {
            (void)hipGetLastError();   // clear sticky error
            hipLaunchKernelGGL(prep_kernel, dim3(KDIM + 64), dim3(256), 0, stream,
                               beta1, obs, Bf8, A8, out);
            hipLaunchKernelGGL(gemm_kernel, dim3(NBLK), dim3(256), 0, stream,
                               obs, beta0, Bf8, (const unsigned char*)A8, out);
        }
    } else {
        double* partials = (double*)d_ws;
        hipLaunchKernelGGL(old_lam_kernel, dim3(NBLK_OLD), dim3(KDIM), 0, stream,
                           obs, beta0, beta1, out, partials);
        hipLaunchKernelGGL(reduce_final_kernel, dim3(1), dim3(256), 0, stream,
                           partials, out, NBLK_OLD);
    }
}

// Round 19
// 34.114 us; speedup vs baseline: 5.0427x; 5.0427x over previous
//
#include <hip/hip_runtime.h>

#define KDIM 256
#define DWIN 20
#define NOBS 8192
#define TAU  20
#define TROWS (NOBS - TAU)          // 8172
#define KTOT  (DWIN * KDIM)         // 5120
#define KS128 (KTOT / 128)          // 40 K-steps of 128
#define QS128 (KS128 / 4)           // 10 per wave (K-quarter)

#define BM 64
#define NBLK_M ((TROWS + BM - 1) / BM)   // 128
#define NBLK   (NBLK_M * 4)              // 512

#define AROWS 83                     // 64 + DWIN - 1
#define APITCH 272                   // 256B data + 16B pad (R10/R13-proven)

#define SH_BYTES 32768               // static shared: A panel 22.6KB / exchange 32KB

typedef float f32x4 __attribute__((ext_vector_type(4)));
typedef int   i32x4 __attribute__((ext_vector_type(4)));
typedef int   i32x8 __attribute__((ext_vector_type(8)));

// ws layout (bytes): Bf8 (1,310,720) | A8 (2,097,152)
#define WS_BF    0u
#define WS_A8    2097152u
#define WS_NEED  (WS_A8 + 2097152u + 8192u)

__device__ __forceinline__ unsigned int pk4_fp8(float a, float b, float c, float d) {
    int lo = __builtin_amdgcn_cvt_pk_fp8_f32(a, b, 0, false);
    return (unsigned int)__builtin_amdgcn_cvt_pk_fp8_f32(c, d, lo, true);
}

// ---------- prep: one block per n-column. B-fragments via transposed LDS
//            (conflict-free, R15/R18-proven) + this block's A8 slice. ----------
// Bf8 layout (verified R10-R18): Bf8[((ks*16+nt)*64 + g*16 + qn)*32 + half*16 + j']
//   = e4m3(B[k][n]), k = ks*128 + g*32 + half*16 + j', n = nt*16 + qn,
//   B[k][n] = beta1[n][k&255][k>>8].
__global__ __launch_bounds__(256)
void prep_kernel(const float* __restrict__ beta1,
                 const float* __restrict__ obs,
                 unsigned char* __restrict__ Bf8,
                 unsigned int* __restrict__ A8,
                 float* __restrict__ out)
{
    __shared__ float L[DWIN * 260];   // L[a*260 + b], 20,800 B; bank-stride 4
    const int n   = blockIdx.x;
    const int tid = threadIdx.x;
    if (n == 0 && tid == 0) out[0] = 0.f;   // zero loglik accumulator

    const float* __restrict__ src = beta1 + (size_t)n * KTOT;
    for (int f = tid; f < KTOT; f += 256) {
        int b = f / DWIN, a = f - b * DWIN;
        L[a * 260 + b] = src[f];
    }
    __syncthreads();

    const int nt = n >> 4, qn = n & 15;
    for (int c = tid; c < KS128 * 8; c += 256) {      // c = ks*8 + g*2 + half
        const int ks = c >> 3, g = (c >> 1) & 3, half = c & 1;
        const int kb = ks * 128 + g * 32 + half * 16;
        const float* Lp = &L[(kb >> 8) * 260 + (kb & 255)];
        i32x4 w;
#pragma unroll
        for (int u = 0; u < 4; ++u) {
            float4 v = *(const float4*)(Lp + u * 4);
            w[u] = (int)pk4_fp8(v.x, v.y, v.z, v.w);
        }
        *(i32x4*)&Bf8[(((size_t)ks * 16 + nt) * 64 + g * 16 + qn) * 32 + half * 16] = w;
    }

    // A8 pack slice: 2048 uints per block (256 blocks x 2048 = full 2MB)
    const int base = n * 2048;
#pragma unroll 2
    for (int u = tid; u < 2048; u += 256) {
        float4 v = ((const float4*)obs)[base + u];
        A8[base + u] = pk4_fp8(v.x, v.y, v.z, v.w);
    }
}

// ---------- gemm block (proven in R18 coop run): LDS A panel from A8,
//            coalesced B-frag stream, K-split 4 waves, barrier-free loop,
//            setprio MFMA clusters, 2-round 32KB exchange ----------
__device__ __forceinline__ void gemm_block(int bid, int tid,
                                           const float* __restrict__ obs,
                                           const float* __restrict__ beta0,
                                           const unsigned char* __restrict__ Bf8,
                                           const unsigned char* __restrict__ A8,
                                           float* __restrict__ out,
                                           char* shbuf)
{
    const int lane = tid & 63;
    const int kq   = tid >> 6;     // wave id: owns K128-steps [10kq, 10kq+10)
    const int g = lane >> 4;
    const int q = lane & 15;
    const int nb = bid & 3;
    const int mb = bid >> 2;
    const int i0 = mb * BM;

    char* ldsA8 = shbuf;           // AROWS x APITCH fp8 (22,576 B)
    const char* bbase = (const char*)Bf8 + (size_t)(nb * 4) * 2048 + (size_t)lane * 32;

#define LOADB8(dst, s)                                                           \
    {                                                                            \
        const char* _p = bbase + (size_t)(10 * kq + ((s) < QS128 ? (s) : QS128 - 1)) * 32768; \
        _Pragma("unroll")                                                        \
        for (int t = 0; t < 4; ++t)                                              \
            dst[t] = *(const i32x8*)(_p + t * 2048);                             \
    }

    i32x8 rbA[4], rbB[4];
    LOADB8(rbA, 0)

    // stage A panel from pre-packed A8 (row stride = 256 BYTES)
    for (int idx = tid; idx < AROWS * 16; idx += 256) {
        const int row = idx >> 4, c16 = idx & 15;
        const int grow = min(i0 + row, NOBS - 1);
        i32x4 v = *(const i32x4*)(A8 + (size_t)grow * 256 + c16 * 16);
        *(i32x4*)(ldsA8 + row * APITCH + c16 * 16) = v;
    }
    __syncthreads();

    f32x4 acc[4][4];
#pragma unroll
    for (int m = 0; m < 4; ++m)
#pragma unroll
        for (int t = 0; t < 4; ++t)
            acc[m][t] = (f32x4){0.f, 0.f, 0.f, 0.f};

#define COMPUTE8(s, breg)                                                        \
    {                                                                            \
        const int _ks = 10 * kq + (s);                                           \
        const int _aro  = _ks >> 1;                                              \
        const int _acol = (_ks & 1) * 128 + g * 32;                              \
        i32x8 _af[4];                                                            \
        _Pragma("unroll")                                                        \
        for (int m = 0; m < 4; ++m)                                              \
            _af[m] = *(const i32x8*)(ldsA8 + (m * 16 + q + _aro) * APITCH + _acol); \
        __builtin_amdgcn_s_setprio(1);                                           \
        _Pragma("unroll")                                                        \
        for (int t = 0; t < 4; ++t)                                              \
            _Pragma("unroll")                                                    \
            for (int m = 0; m < 4; ++m)                                          \
                acc[m][t] = __builtin_amdgcn_mfma_scale_f32_16x16x128_f8f6f4(    \
                    _af[m], (breg)[t], acc[m][t], 0, 0, 0, 0x7f, 0, 0x7f);       \
        __builtin_amdgcn_s_setprio(0);                                           \
    }

#pragma unroll 1
    for (int s = 0; s < QS128; s += 2) {
        LOADB8(rbB, s + 1)
        COMPUTE8(s, rbA)
        if (s + 2 < QS128) LOADB8(rbA, s + 2)
        COMPUTE8(s + 1, rbB)
    }

    // --- 2-round m-half exchange (32KB peak), wave kq reads band kq ---
    f32x4* pc = (f32x4*)shbuf;
    f32x4 bsum[4] = {};
#pragma unroll
    for (int r2 = 0; r2 < 2; ++r2) {
        __syncthreads();                        // pc region free
#pragma unroll
        for (int m2 = 0; m2 < 2; ++m2)
#pragma unroll
            for (int t = 0; t < 4; ++t)
                pc[((kq * 8 + m2 * 4 + t) << 6) + lane] = acc[2 * r2 + m2][t];
        __syncthreads();
        if ((kq >> 1) == r2) {
            const int m2 = kq & 1;
#pragma unroll
            for (int t = 0; t < 4; ++t) {
                f32x4 ssum = pc[((m2 * 4 + t) << 6) + lane];
#pragma unroll
                for (int wp = 1; wp < 4; ++wp)
                    ssum += pc[((wp * 8 + m2 * 4 + t) << 6) + lane];
                bsum[t] = ssum;
            }
        }
    }
    __syncthreads();                            // all pc reads complete

    // --- fused epilogue: wave kq writes band m=kq (rows i0+kq*16 .. +15) ---
    double part = 0.0;
#pragma unroll
    for (int t = 0; t < 4; ++t) {
        const int col = nb * 64 + t * 16 + q;
        const float b0v = beta0[col];
#pragma unroll
        for (int r = 0; r < 4; ++r) {
            const int row = i0 + kq * 16 + 4 * g + r;   // C/D: row=(lane>>4)*4+reg
            if (row < TROWS) {
                float lam = bsum[t][r] + b0v;
                out[1 + (size_t)row * KDIM + col] = lam;
                float o = obs[(size_t)(row + TAU) * KDIM + col];
                part += (double)o * (double)__logf(lam) - (double)lam;
            }
        }
    }

#pragma unroll
    for (int off = 32; off > 0; off >>= 1) part += __shfl_down(part, off, 64);
    double* sred = (double*)shbuf;              // overlaps pc (post-barrier safe)
    if (lane == 0) sred[kq] = part;
    __syncthreads();
    if (tid == 0)
        atomicAdd(out, (float)(sred[0] + sred[1] + sred[2] + sred[3]));
}

__global__ __launch_bounds__(256, 2)
void gemm_kernel(const float* __restrict__ obs,
                 const float* __restrict__ beta0,
                 const unsigned char* __restrict__ Bf8,
                 const unsigned char* __restrict__ A8,
                 float* __restrict__ out)
{
    __shared__ char shbuf[SH_BYTES];
    gemm_block(blockIdx.x, threadIdx.x, obs, beta0, Bf8, A8, out, shbuf);
}

// ================= fallback fp32 path (R1, proven) =================
#define BM_OLD 16
#define NBLK_OLD ((TROWS + BM_OLD - 1) / BM_OLD)   // 511

__global__ __launch_bounds__(KDIM, 2)
void old_lam_kernel(const float* __restrict__ obs,
                    const float* __restrict__ beta0,
                    const float* __restrict__ beta1,
                    float* __restrict__ out,
                    double* __restrict__ partials)
{
    const int k  = threadIdx.x;
    const int i0 = blockIdx.x * BM_OLD;
    const int nr = min(BM_OLD, TROWS - i0);
    const int smax = nr + DWIN - 1;

    float acc[BM_OLD];
#pragma unroll
    for (int r = 0; r < BM_OLD; ++r) acc[r] = 0.f;

    const float* __restrict__ b1k = beta1 + (size_t)k * (KDIM * DWIN);

    for (int b = 0; b < KDIM; ++b) {
        float br[DWIN];
        const float4* qd = (const float4*)(b1k + b * DWIN);
#pragma unroll
        for (int v = 0; v < DWIN / 4; ++v) {
            float4 t = qd[v];
            br[4*v+0] = t.x; br[4*v+1] = t.y; br[4*v+2] = t.z; br[4*v+3] = t.w;
        }
        float wv[BM_OLD + DWIN - 1];
#pragma unroll
        for (int s = 0; s < BM_OLD + DWIN - 1; ++s)
            wv[s] = (s < smax) ? obs[(size_t)(i0 + s) * KDIM + b] : 0.f;
#pragma unroll
        for (int r = 0; r < BM_OLD; ++r)
#pragma unroll
            for (int a = 0; a < DWIN; ++a)
                acc[r] = fmaf(wv[r + a], br[a], acc[r]);
    }

    const float b0 = beta0[k];
    double part = 0.0;
    for (int r = 0; r < nr; ++r) {
        float lam = acc[r] + b0;
        out[1 + (size_t)(i0 + r) * KDIM + k] = lam;
        float o = obs[(size_t)(i0 + r + TAU) * KDIM + k];
        part += (double)(o * logf(lam) - lam);
    }

    __shared__ double sred2[KDIM];
    sred2[k] = part;
    __syncthreads();
    for (int off = KDIM / 2; off > 0; off >>= 1) {
        if (k < off) sred2[k] += sred2[k + off];
        __syncthreads();
    }
    if (k == 0) partials[blockIdx.x] = sred2[0];
}

__global__ void reduce_final_kernel(const double* __restrict__ partials,
                                    float* __restrict__ out, int n)
{
    __shared__ double sr[256];
    double v = 0.0;
    for (int i = threadIdx.x; i < n; i += 256) v += partials[i];
    sr[threadIdx.x] = v;
    __syncthreads();
    for (int off = 128; off > 0; off >>= 1) {
        if (threadIdx.x < off) sr[threadIdx.x] += sr[threadIdx.x + off];
        __syncthreads();
    }
    if (threadIdx.x == 0) out[0] = (float)sr[0];
}
// ===================================================================

extern "C" void kernel_launch(void* const* d_in, const int* in_sizes, int n_in,
                              void* d_out, int out_size, void* d_ws, size_t ws_size,
                              hipStream_t stream)
{
    const float* obs   = (const float*)d_in[0];
    const float* beta0 = (const float*)d_in[1];
    const float* beta1 = (const float*)d_in[2];
    float* out = (float*)d_out;

    if (ws_size >= (size_t)WS_NEED) {
        unsigned char* Bf8 = (unsigned char*)d_ws + WS_BF;
        unsigned int*  A8  = (unsigned int*)((char*)d_ws + WS_A8);

        hipLaunchKernelGGL(prep_kernel, dim3(KDIM), dim3(256), 0, stream,
                           beta1, obs, Bf8, A8, out);
        hipLaunchKernelGGL(gemm_kernel, dim3(NBLK), dim3(256), 0, stream,
                           obs, beta0, Bf8, (const unsigned char*)A8, out);
    } else {
        double* partials = (double*)d_ws;
        hipLaunchKernelGGL(old_lam_kernel, dim3(NBLK_OLD), dim3(KDIM), 0, stream,
                           obs, beta0, beta1, out, partials);
        hipLaunchKernelGGL(reduce_final_kernel, dim3(1), dim3(256), 0, stream,
                           partials, out, NBLK_OLD);
    }
}

// Round 20
// 32.033 us; speedup vs baseline: 5.3704x; 1.0650x over previous
//
#include <hip/hip_runtime.h>

#define KDIM 256
#define DWIN 20
#define NOBS 8192
#define TAU  20
#define TROWS (NOBS - TAU)          // 8172
#define KTOT  (DWIN * KDIM)         // 5120
#define KS128 (KTOT / 128)          // 40 K-steps of 128
#define QS128 (KS128 / 4)           // 10 per wave (K-quarter)

#define BM 64
#define NBLK_M ((TROWS + BM - 1) / BM)   // 128
#define NBLK   (NBLK_M * 4)              // 512 -> 2 blocks/CU

#define AROWS 83                     // 64 + DWIN - 1
#define APITCH 272                   // 256B data + 16B pad (R10/R13-proven)

#define PC_BYTES  65536
#define SRED_OFF  PC_BYTES
#define DYN_TOTAL (PC_BYTES + 64)

typedef float f32x4 __attribute__((ext_vector_type(4)));
typedef int   i32x4 __attribute__((ext_vector_type(4)));
typedef int   i32x8 __attribute__((ext_vector_type(8)));

// ws layout (bytes): Bf8 (1,310,720) | A8 (2,097,152)
#define WS_BF    0u
#define WS_A8    2097152u
#define WS_NEED  (WS_A8 + 2097152u + 8192u)

__device__ __forceinline__ unsigned int pk4_fp8(float a, float b, float c, float d) {
    int lo = __builtin_amdgcn_cvt_pk_fp8_f32(a, b, 0, false);
    return (unsigned int)__builtin_amdgcn_cvt_pk_fp8_f32(c, d, lo, true);
}

// ---- prep: blocks [0,256) -> B fragments via TRANSPOSED LDS (conflict-free);
//      blocks [256,320) -> A8 row-major fp8 pack (verified R12/R13) ----
// Bf8 layout (verified R10-R14): Bf8[((ks*16+nt)*64 + g*16 + qn)*32 + half*16 + j']
//   holds e4m3(B[k][n]), k = ks*128 + g*32 + half*16 + j', n = nt*16 + qn,
//   B[k][n] = beta1[n][k&255][k>>8].
__global__ __launch_bounds__(256)
void prep_kernel(const float* __restrict__ beta1,
                 const float* __restrict__ obs,
                 unsigned char* __restrict__ Bf8,
                 unsigned int* __restrict__ A8,
                 float* __restrict__ out)
{
    const int tid = threadIdx.x;
    if (blockIdx.x >= KDIM) {
        const int base = (blockIdx.x - KDIM) * 8192;
#pragma unroll 4
        for (int u = tid; u < 8192; u += 256) {
            float4 v = ((const float4*)obs)[base + u];
            A8[base + u] = pk4_fp8(v.x, v.y, v.z, v.w);
        }
        return;
    }

    // transposed row: L[a*260 + b] = beta1[n][b][a]; 260=4*65 keeps float4
    // 16B-aligned for every a; bank stride 4 -> gather reads conflict-free.
    __shared__ float L[DWIN * 260];   // 20,800 B
    const int n = blockIdx.x;
    if (n == 0 && tid == 0) out[0] = 0.f;   // zero loglik accumulator

    const float* __restrict__ src = beta1 + (size_t)n * KTOT;
    for (int f = tid; f < KTOT; f += 256) {
        int b = f / DWIN, a = f - b * DWIN;
        L[a * 260 + b] = src[f];
    }
    __syncthreads();

    const int nt = n >> 4, qn = n & 15;
    for (int c = tid; c < KS128 * 8; c += 256) {      // c = ks*8 + g*2 + half
        const int ks = c >> 3, g = (c >> 1) & 3, half = c & 1;
        const int kb = ks * 128 + g * 32 + half * 16; // 16-aligned, never crosses 256
        const int a = kb >> 8, b0 = kb & 255;
        const float* Lp = &L[a * 260 + b0];
        i32x4 w;
#pragma unroll
        for (int u = 0; u < 4; ++u) {
            float4 v = *(const float4*)(Lp + u * 4);  // 16 consecutive floats
            w[u] = (int)pk4_fp8(v.x, v.y, v.z, v.w);
        }
        *(i32x4*)&Bf8[(((size_t)ks * 16 + nt) * 64 + g * 16 + qn) * 32 + half * 16] = w;
    }
}

extern __shared__ char dynlds[];

// ---- main GEMM (R13-proven structure): LDS A panel staged from pre-packed
//      A8, coalesced B-frag stream, K-split 4 waves, barrier-free loop.
//      Direct i32x8 loads for BOTH A (LDS) and B (global). ----
__global__ __launch_bounds__(256, 2)
void gemm_kernel(const float* __restrict__ obs,
                 const float* __restrict__ beta0,
                 const unsigned char* __restrict__ Bf8,
                 const unsigned char* __restrict__ A8,
                 float* __restrict__ out)
{
    const int tid  = threadIdx.x;
    const int lane = tid & 63;
    const int kq   = tid >> 6;     // wave id: owns K128-steps [10kq, 10kq+10)
    const int g = lane >> 4;
    const int q = lane & 15;
    const int nb = blockIdx.x & 3;
    const int mb = blockIdx.x >> 2;
    const int i0 = mb * BM;

    char* ldsA8 = dynlds;          // AROWS x APITCH fp8
    const char* bbase = (const char*)Bf8 + (size_t)(nb * 4) * 2048 + (size_t)lane * 32;

#define LOADB8(dst, s)                                                           \
    {                                                                            \
        const char* _p = bbase + (size_t)(10 * kq + ((s) < QS128 ? (s) : QS128 - 1)) * 32768; \
        _Pragma("unroll")                                                        \
        for (int t = 0; t < 4; ++t)                                              \
            dst[t] = *(const i32x8*)(_p + t * 2048);                             \
    }

    i32x8 rbA[4], rbB[4];
    LOADB8(rbA, 0)

    // --- stage A panel from A8: 83 rows x 16 chunks of 16B, coalesced copy ---
    for (int idx = tid; idx < AROWS * 16; idx += 256) {
        const int row = idx >> 4, c16 = idx & 15;
        const int grow = min(i0 + row, NOBS - 1);
        i32x4 v = *(const i32x4*)(A8 + (size_t)grow * 256 + c16 * 16);
        *(i32x4*)(ldsA8 + row * APITCH + c16 * 16) = v;
    }
    __syncthreads();

    f32x4 acc[4][4];
#pragma unroll
    for (int m = 0; m < 4; ++m)
#pragma unroll
        for (int t = 0; t < 4; ++t)
            acc[m][t] = (f32x4){0.f, 0.f, 0.f, 0.f};

#define COMPUTE8(s, breg)                                                        \
    {                                                                            \
        const int _ks = 10 * kq + (s);                                           \
        const int _aro  = _ks >> 1;                                              \
        const int _acol = (_ks & 1) * 128 + g * 32;                              \
        i32x8 _af[4];                                                            \
        _Pragma("unroll")                                                        \
        for (int m = 0; m < 4; ++m)                                              \
            _af[m] = *(const i32x8*)(ldsA8 + (m * 16 + q + _aro) * APITCH + _acol); \
        _Pragma("unroll")                                                        \
        for (int t = 0; t < 4; ++t)                                              \
            _Pragma("unroll")                                                    \
            for (int m = 0; m < 4; ++m)                                          \
                acc[m][t] = __builtin_amdgcn_mfma_scale_f32_16x16x128_f8f6f4(    \
                    _af[m], (breg)[t], acc[m][t], 0, 0, 0, 0x7f, 0, 0x7f);       \
    }

#pragma unroll 1
    for (int s = 0; s < QS128; s += 2) {
        LOADB8(rbB, s + 1)
        COMPUTE8(s, rbA)
        if (s + 2 < QS128) LOADB8(rbA, s + 2)
        COMPUTE8(s + 1, rbB)
    }

    // --- exchange partial C through LDS (reuses A region) ---
    __syncthreads();
    f32x4* pc = (f32x4*)dynlds;        // 4096 x 16B = 64KB
#pragma unroll
    for (int m = 0; m < 4; ++m)
#pragma unroll
        for (int t = 0; t < 4; ++t)
            pc[((kq * 16 + m * 4 + t) << 6) + lane] = acc[m][t];
    __syncthreads();

    // wave kq reduces band m=kq, fused epilogue
    double part = 0.0;
#pragma unroll
    for (int t = 0; t < 4; ++t) {
        f32x4 sum = pc[((kq * 4 + t) << 6) + lane];
#pragma unroll
        for (int wp = 1; wp < 4; ++wp)
            sum += pc[((wp * 16 + kq * 4 + t) << 6) + lane];
        const int col = nb * 64 + t * 16 + q;
        const float b0v = beta0[col];
#pragma unroll
        for (int r = 0; r < 4; ++r) {
            const int row = i0 + kq * 16 + 4 * g + r;   // C/D: row=(lane>>4)*4+reg
            if (row < TROWS) {
                float lam = sum[r] + b0v;
                out[1 + (size_t)row * KDIM + col] = lam;
                float o = obs[(size_t)(row + TAU) * KDIM + col];
                part += (double)o * (double)__logf(lam) - (double)lam;
            }
        }
    }

#pragma unroll
    for (int off = 32; off > 0; off >>= 1) part += __shfl_down(part, off, 64);
    double* sred = (double*)(dynlds + SRED_OFF);
    if (lane == 0) sred[kq] = part;
    __syncthreads();
    if (tid == 0)
        atomicAdd(out, (float)(sred[0] + sred[1] + sred[2] + sred[3]));
}

// ================= fallback fp32 path (R1, proven) =================
#define BM_OLD 16
#define NBLK_OLD ((TROWS + BM_OLD - 1) / BM_OLD)   // 511

__global__ __launch_bounds__(KDIM, 2)
void old_lam_kernel(const float* __restrict__ obs,
                    const float* __restrict__ beta0,
                    const float* __restrict__ beta1,
                    float* __restrict__ out,
                    double* __restrict__ partials)
{
    const int k  = threadIdx.x;
    const int i0 = blockIdx.x * BM_OLD;
    const int nr = min(BM_OLD, TROWS - i0);
    const int smax = nr + DWIN - 1;

    float acc[BM_OLD];
#pragma unroll
    for (int r = 0; r < BM_OLD; ++r) acc[r] = 0.f;

    const float* __restrict__ b1k = beta1 + (size_t)k * (KDIM * DWIN);

    for (int b = 0; b < KDIM; ++b) {
        float br[DWIN];
        const float4* qd = (const float4*)(b1k + b * DWIN);
#pragma unroll
        for (int v = 0; v < DWIN / 4; ++v) {
            float4 t = qd[v];
            br[4*v+0] = t.x; br[4*v+1] = t.y; br[4*v+2] = t.z; br[4*v+3] = t.w;
        }
        float wv[BM_OLD + DWIN - 1];
#pragma unroll
        for (int s = 0; s < BM_OLD + DWIN - 1; ++s)
            wv[s] = (s < smax) ? obs[(size_t)(i0 + s) * KDIM + b] : 0.f;
#pragma unroll
        for (int r = 0; r < BM_OLD; ++r)
#pragma unroll
            for (int a = 0; a < DWIN; ++a)
                acc[r] = fmaf(wv[r + a], br[a], acc[r]);
    }

    const float b0 = beta0[k];
    double part = 0.0;
    for (int r = 0; r < nr; ++r) {
        float lam = acc[r] + b0;
        out[1 + (size_t)(i0 + r) * KDIM + k] = lam;
        float o = obs[(size_t)(i0 + r + TAU) * KDIM + k];
        part += (double)(o * logf(lam) - lam);
    }

    __shared__ double sred2[KDIM];
    sred2[k] = part;
    __syncthreads();
    for (int off = KDIM / 2; off > 0; off >>= 1) {
        if (k < off) sred2[k] += sred2[k + off];
        __syncthreads();
    }
    if (k == 0) partials[blockIdx.x] = sred2[0];
}

__global__ void reduce_final_kernel(const double* __restrict__ partials,
                                    float* __restrict__ out, int n)
{
    __shared__ double sr[256];
    double v = 0.0;
    for (int i = threadIdx.x; i < n; i += 256) v += partials[i];
    sr[threadIdx.x] = v;
    __syncthreads();
    for (int off = 128; off > 0; off >>= 1) {
        if (threadIdx.x < off) sr[threadIdx.x] += sr[threadIdx.x + off];
        __syncthreads();
    }
    if (threadIdx.x == 0) out[0] = (float)sr[0];
}
// ===================================================================

extern "C" void kernel_launch(void* const* d_in, const int* in_sizes, int n_in,
                              void* d_out, int out_size, void* d_ws, size_t ws_size,
                              hipStream_t stream)
{
    const float* obs   = (const float*)d_in[0];
    const float* beta0 = (const float*)d_in[1];
    const float* beta1 = (const float*)d_in[2];
    float* out = (float*)d_out;

    if (ws_size >= (size_t)WS_NEED) {
        unsigned char* Bf8 = (unsigned char*)d_ws + WS_BF;
        unsigned int*  A8  = (unsigned int*)((char*)d_ws + WS_A8);

        (void)hipFuncSetAttribute(reinterpret_cast<const void*>(gemm_kernel),
                                  hipFuncAttributeMaxDynamicSharedMemorySize,
                                  DYN_TOTAL);

        hipLaunchKernelGGL(prep_kernel, dim3(KDIM + 64), dim3(256), 0, stream,
                           beta1, obs, Bf8, A8, out);
        hipLaunchKernelGGL(gemm_kernel, dim3(NBLK), dim3(256), DYN_TOTAL, stream,
                           obs, beta0, Bf8, (const unsigned char*)A8, out);
    } else {
        double* partials = (double*)d_ws;
        hipLaunchKernelGGL(old_lam_kernel, dim3(NBLK_OLD), dim3(KDIM), 0, stream,
                           obs, beta0, beta1, out, partials);
        hipLaunchKernelGGL(reduce_final_kernel, dim3(1), dim3(256), 0, stream,
                           partials, out, NBLK_OLD);
    }
}